// Round 3
// baseline (384.818 us; speedup 1.0000x reference)
//
#include <hip/hip_runtime.h>
#include <math.h>

// DeepMMD round 3: joint 8192x8192 symmetric pass, 128x128 tiles, 2080 blocks.
// Wave-private epilogue (no __syncthreads), packed-fp32 phase F, 33.8KB LDS,
// launch_bounds(256,3) for 3 blocks/CU. MLP k-split 8-way across 256 blocks.

#define N_S 4096
#define LOG2E 1.4426950408889634

typedef _Float16 v8h __attribute__((ext_vector_type(8)));
typedef float v16f __attribute__((ext_vector_type(16)));
typedef float v2f __attribute__((ext_vector_type(2)));

union U16 { uint4 u; v8h h; };

// wave-internal LDS sync: all lanes of a wave execute in lockstep; lgkmcnt(0)
// guarantees this wave's ds_writes are visible to its own subsequent ds_reads.
#define WAVE_LDS_SYNC() do {                                   \
    __builtin_amdgcn_wave_barrier();                           \
    asm volatile("s_waitcnt lgkmcnt(0)" ::: "memory");         \
    __builtin_amdgcn_wave_barrier();                           \
} while (0)

// ---------------- MLP: 256 blocks x 256 thr, 32 rows/block, k-split 8 ----------------
__global__ __launch_bounds__(256)
void mlp_kernel(const float* __restrict__ X, const float* __restrict__ Y,
                const float* __restrict__ W1, const float* __restrict__ b1,
                const float* __restrict__ W2, const float* __restrict__ b2,
                const float* __restrict__ W3, const float* __restrict__ b3,
                const float* __restrict__ W4, const float* __restrict__ b4,
                const float* __restrict__ sq,
                float* __restrict__ featsT, float* __restrict__ wOrg)
{
    __shared__ double sh[32 * 8 * 11];   // [row][chunk][z0..z9, nrm]
    int tid = threadIdx.x;
    int kk = tid & 7, r8 = tid >> 3;
    int row = blockIdx.x * 32 + r8;
    const float* xr = (row < N_S) ? (X + (size_t)row * 256) : (Y + (size_t)(row - N_S) * 256);

    double z[10];
#pragma unroll
    for (int j = 0; j < 10; ++j) z[j] = 0.0;
    double nrm = 0.0;
    for (int k4 = 0; k4 < 8; ++k4) {
        int kbase = kk * 32 + k4 * 4;
        float4 xv4 = *(const float4*)(xr + kbase);
        double xv[4] = {(double)xv4.x, (double)xv4.y, (double)xv4.z, (double)xv4.w};
#pragma unroll
        for (int u = 0; u < 4; ++u) {
            nrm += xv[u] * xv[u];
#pragma unroll
            for (int j = 0; j < 10; ++j) z[j] += xv[u] * (double)W1[(kbase + u) * 10 + j];
        }
    }
    double* slot = sh + (size_t)(r8 * 8 + kk) * 11;
#pragma unroll
    for (int j = 0; j < 10; ++j) slot[j] = z[j];
    slot[10] = nrm;
    __syncthreads();

    if (tid < 32) {
        int r = blockIdx.x * 32 + tid;
        double zz[10], nr = 0.0;
#pragma unroll
        for (int j = 0; j < 10; ++j) zz[j] = (double)b1[j];
        for (int s = 0; s < 8; ++s) {
            const double* p = sh + (size_t)(tid * 8 + s) * 11;
#pragma unroll
            for (int j = 0; j < 10; ++j) zz[j] += p[j];
            nr += p[10];
        }
#pragma unroll
        for (int j = 0; j < 10; ++j) zz[j] = fmax(zz[j], 0.0) + log1p(exp(-fabs(zz[j])));

        double z2[10];
#pragma unroll
        for (int j = 0; j < 10; ++j) z2[j] = (double)b2[j];
#pragma unroll
        for (int k = 0; k < 10; ++k)
#pragma unroll
            for (int j = 0; j < 10; ++j) z2[j] += zz[k] * (double)W2[k * 10 + j];
#pragma unroll
        for (int j = 0; j < 10; ++j) z2[j] = fmax(z2[j], 0.0) + log1p(exp(-fabs(z2[j])));

        double z3[10];
#pragma unroll
        for (int j = 0; j < 10; ++j) z3[j] = (double)b3[j];
#pragma unroll
        for (int k = 0; k < 10; ++k)
#pragma unroll
            for (int j = 0; j < 10; ++j) z3[j] += z2[k] * (double)W3[k * 10 + j];
#pragma unroll
        for (int j = 0; j < 10; ++j) z3[j] = fmax(z3[j], 0.0) + log1p(exp(-fabs(z3[j])));

        for (int j = 0; j < 50; ++j) {
            double f = (double)b4[j];
#pragma unroll
            for (int k = 0; k < 10; ++k) f += z3[k] * (double)W4[k * 50 + j];
            featsT[(size_t)j * 8192 + r] = (float)f;
        }
        featsT[(size_t)50 * 8192 + r] = 0.0f;
        featsT[(size_t)51 * 8192 + r] = 0.0f;

        double sqv = (double)sq[0];
        wOrg[r] = (float)exp2(-nr * (LOG2E / (sqv * sqv)));
    }
}

// ---------------- helpers ----------------
__device__ __forceinline__ v8h ldfrag(const uint4* buf, int s, int g) {
    U16 t; t.u = buf[s * 4 + (g ^ (s & 3))];
    return t.h;
}

__device__ __forceinline__ void cvt_split(float4 f0, float4 f1, uint4* hi, uint4* lo) {
    U16 H, L;
    float fv[8] = {f0.x, f0.y, f0.z, f0.w, f1.x, f1.y, f1.z, f1.w};
#pragma unroll
    for (int u = 0; u < 8; ++u) {
        _Float16 h = (_Float16)fv[u];
        H.h[u] = h;
        L.h[u] = (_Float16)(fv[u] - (float)h);
    }
    *hi = H.u; *lo = L.u;
}

// ---------------- joint pairwise pass ----------------
__global__ __launch_bounds__(256, 3)
void pair_kernel(const float* __restrict__ X, const float* __restrict__ Y,
                 const float* __restrict__ featsT, const float* __restrict__ wOrg,
                 const float* __restrict__ ep, const float* __restrict__ sq,
                 const float* __restrict__ sph,
                 float* __restrict__ D8, double* __restrict__ S)
{
    // LDS: phaseF FA/FB 26x132 f32 x2 = 27456 | phaseA 4x512 uint4 = 32768
    //      epilogue: 4 waves x (16x132 f32 = 8448) = 33792
    __shared__ __align__(16) char smem[33792];

    int tid = threadIdx.x;
    int lane = tid & 63, w = tid >> 6;
    int h = lane >> 5, l31 = lane & 31, l15 = lane & 15, rg = lane >> 4;

    // upper-triangle tile decode
    int L = blockIdx.x, it = 0, span = 64;
    while (L >= span) { L -= span; --span; ++it; }
    int jt = it + L;

    bool sameHalf = (jt < 32) || (it >= 32);
    bool isDiag = (it == jt);
    bool isTrace = (jt == it + 32);
    int region = (jt < 32) ? 0 : ((it >= 32) ? 1 : 2);
    float sgn = sameHalf ? 1.0f : -1.0f;
    int i0 = it * 128, j0 = jt * 128;
    const float* aorg = (it < 32) ? X + (size_t)i0 * 256 : Y + (size_t)(i0 - N_S) * 256;
    const float* borg = (jt < 32) ? X + (size_t)j0 * 256 : Y + (size_t)(j0 - N_S) * 256;

    double epd = (double)ep[0];
    double eps = 1.0 / (1.0 + exp(-epd));
    double sqv = (double)sq[0], spv = (double)sph[0];
    float cf = (float)(LOG2E / (spv * spv));
    float twoco = (float)(2.0 * LOG2E / (sqv * sqv));
    float epsv = (float)eps, ome = (float)(1.0 - eps);

    // ---- phase F: exact fp32 feature distances, packed fp32 ----
    // wave w owns rows [32w,32w+32); lane: rows 32w+rg*8..+8, cols l15*8..+8
    float* FA = (float*)smem;
    float* FB = FA + 26 * 132;
    v2f da[8][4];
#pragma unroll
    for (int i = 0; i < 8; ++i)
#pragma unroll
        for (int j = 0; j < 4; ++j) da[i][j] = (v2f)(0.0f);

    int frow = 32 * w + rg * 8;
    int fcol = l15 * 8;
    for (int c0f = 0; c0f < 52; c0f += 26) {
        __syncthreads();
        for (int idx = tid; idx < 832; idx += 256) {   // 26 dims x 32 float4
            int k = idx >> 5, cg = (idx & 31) * 4;
            *(float4*)&FA[k * 132 + cg] = *(const float4*)&featsT[(size_t)(c0f + k) * 8192 + i0 + cg];
            *(float4*)&FB[k * 132 + cg] = *(const float4*)&featsT[(size_t)(c0f + k) * 8192 + j0 + cg];
        }
        __syncthreads();
        for (int k = 0; k < 26; ++k) {
            float4 a0 = *(const float4*)&FA[k * 132 + frow];
            float4 a1 = *(const float4*)&FA[k * 132 + frow + 4];
            float4 b0 = *(const float4*)&FB[k * 132 + fcol];
            float4 b1 = *(const float4*)&FB[k * 132 + fcol + 4];
            float av[8] = {a0.x, a0.y, a0.z, a0.w, a1.x, a1.y, a1.z, a1.w};
            v2f bb[4];
            bb[0][0] = b0.x; bb[0][1] = b0.y; bb[1][0] = b0.z; bb[1][1] = b0.w;
            bb[2][0] = b1.x; bb[2][1] = b1.y; bb[3][0] = b1.z; bb[3][1] = b1.w;
#pragma unroll
            for (int i = 0; i < 8; ++i) {
                v2f ai; ai[0] = av[i]; ai[1] = av[i];
#pragma unroll
                for (int j = 0; j < 4; ++j) {
                    v2f t = ai - bb[j];
                    da[i][j] = t * t + da[i][j];
                }
            }
        }
    }
    // d -> e2
#pragma unroll
    for (int i = 0; i < 8; ++i)
#pragma unroll
        for (int j = 0; j < 4; ++j) {
            da[i][j][0] = exp2f(-da[i][j][0] * cf);
            da[i][j][1] = exp2f(-da[i][j][1] * cf);
        }

    // ---- phase A: fp16-split MFMA org dot; wave w: rows [32w,+32) x cols all ----
    uint4* Ahi = (uint4*)smem;
    uint4* Alo = Ahi + 512;
    uint4* Bhi = Ahi + 1024;
    uint4* Blo = Ahi + 1536;

    v16f acc[4];
#pragma unroll
    for (int c = 0; c < 4; ++c) acc[c] = (v16f)(0.0f);

    for (int kb = 0; kb < 256; kb += 32) {
        __syncthreads();
        for (int idx2 = tid; idx2 < 512; idx2 += 256) {
            int r = idx2 >> 2, g = idx2 & 3;
            int sw = r * 4 + (g ^ (r & 3));
            const float* pa = aorg + (size_t)r * 256 + kb + g * 8;
            const float* pb = borg + (size_t)r * 256 + kb + g * 8;
            float4 fa0 = *(const float4*)pa, fa1 = *(const float4*)(pa + 4);
            float4 fb0 = *(const float4*)pb, fb1 = *(const float4*)(pb + 4);
            uint4 hi, lo;
            cvt_split(fa0, fa1, &hi, &lo); Ahi[sw] = hi; Alo[sw] = lo;
            cvt_split(fb0, fb1, &hi, &lo); Bhi[sw] = hi; Blo[sw] = lo;
        }
        __syncthreads();
#pragma unroll
        for (int ks = 0; ks < 2; ++ks) {
            int g = ks * 2 + h;
            int rs = 32 * w + l31;
            v8h ah = ldfrag(Ahi, rs, g);
            v8h al = ldfrag(Alo, rs, g);
#pragma unroll
            for (int c = 0; c < 4; ++c) {
                v8h bh = ldfrag(Bhi, 32 * c + l31, g);
                v8h bl = ldfrag(Blo, 32 * c + l31, g);
                acc[c] = __builtin_amdgcn_mfma_f32_32x32x16_f16(al, bh, acc[c], 0, 0, 0);
                acc[c] = __builtin_amdgcn_mfma_f32_32x32x16_f16(ah, bl, acc[c], 0, 0, 0);
                acc[c] = __builtin_amdgcn_mfma_f32_32x32x16_f16(ah, bh, acc[c], 0, 0, 0);
            }
        }
    }
    __syncthreads();   // all phase-A LDS reads done before epilogue overwrite

    // ---- epilogue: wave-private, 2 rounds of 16 rows, no block barriers ----
    float* EB = (float*)(smem + w * 8448);   // 16 x 132
    double bsum = 0.0, trd = 0.0;
    float colacc[4] = {0, 0, 0, 0};
    float wbc[4];
#pragma unroll
    for (int c = 0; c < 4; ++c) wbc[c] = wOrg[j0 + 32 * c + l31];

#pragma unroll
    for (int r = 0; r < 2; ++r) {
        WAVE_LDS_SYNC();     // prior round's reads complete before overwrite
        if ((rg >> 1) == r) {
            int rbase = (rg & 1) * 8;
#pragma unroll
            for (int i = 0; i < 8; ++i) {
                float4 v0, v1;
                v0.x = da[i][0][0]; v0.y = da[i][0][1]; v0.z = da[i][1][0]; v0.w = da[i][1][1];
                v1.x = da[i][2][0]; v1.y = da[i][2][1]; v1.z = da[i][3][0]; v1.w = da[i][3][1];
                *(float4*)&EB[(rbase + i) * 132 + fcol] = v0;
                *(float4*)&EB[(rbase + i) * 132 + fcol + 4] = v1;
            }
        }
        WAVE_LDS_SYNC();
#pragma unroll
        for (int q = 0; q < 8; ++q) {
            int reg = 8 * r + q;
            int row_local = (q & 3) + 8 * (q >> 2) + 4 * h;   // [0,16)
            int tile_row = 32 * w + 16 * r + row_local;
            float waq = wOrg[i0 + tile_row];
            float rsum = 0.0f;
#pragma unroll
            for (int c = 0; c < 4; ++c) {
                int col = 32 * c + l31;
                float e2 = EB[row_local * 132 + col];
                float G = acc[c][reg];
                float kv = waq * wbc[c] * exp2f(G * twoco) * (ome * e2 + epsv);
                if (isDiag && tile_row == col) kv = 0.0f;
                if (isTrace && col == tile_row) trd += (double)kv;
                bsum += (double)kv;
                rsum += kv;
                colacc[c] += kv;
            }
            // row sum: butterfly over the 32 lanes sharing this h
#pragma unroll
            for (int m = 1; m < 32; m <<= 1) rsum += __shfl_xor(rsum, m, 64);
            if (l31 == q) atomicAdd(&D8[i0 + tile_row], sgn * rsum);
        }
        WAVE_LDS_SYNC();     // reads done before next round's writes
    }

    // column sums (skip on diagonal tiles)
    if (!isDiag) {
#pragma unroll
        for (int c = 0; c < 4; ++c) {
            float v = colacc[c] + __shfl_xor(colacc[c], 32, 64);
            if (h == 0) atomicAdd(&D8[j0 + 32 * c + l31], sgn * v);
        }
    }

    // total sum
#pragma unroll
    for (int m = 1; m < 64; m <<= 1) bsum += __shfl_xor(bsum, m, 64);
    if (lane == 0) {
        double wgt = (sameHalf && !isDiag) ? 2.0 : 1.0;
        atomicAdd(&S[region], wgt * bsum);
    }
    if (isTrace) {
#pragma unroll
        for (int m = 1; m < 64; m <<= 1) trd += __shfl_xor(trd, m, 64);
        if (lane == 0) atomicAdd(&S[3], trd);
    }
}

// ---------------- final scalar assembly ----------------
__global__ __launch_bounds__(256)
void final_kernel(const float* __restrict__ D8, const double* __restrict__ S,
                  float* __restrict__ out)
{
    __shared__ double buf[512];
    int tid = threadIdx.x;
    double sD = 0, sD2 = 0;
    for (int i = tid; i < 4096; i += 256) {
        double d = (double)D8[i] + (double)D8[i + 4096];
        sD += d; sD2 += d * d;
    }
    buf[tid] = sD; buf[256 + tid] = sD2;
    __syncthreads();
    for (int s = 128; s > 0; s >>= 1) {
        if (tid < s) { buf[tid] += buf[tid + s]; buf[256 + tid] += buf[256 + tid + s]; }
        __syncthreads();
    }
    if (tid == 0) {
        double n = (double)N_S, D = n * (n - 1.0);
        double xx = S[0] / D, yy = S[1] / D, xy = (S[2] - S[3]) / D;
        double mmd2 = xx - 2.0 * xy + yy;
        double sumd = buf[0], sumd2 = buf[256];
        double sumh = 2.0 * n + sumd;                    // hs_i = 2 + delta_i
        double sumhs2 = 4.0 * n + 4.0 * sumd + sumd2;
        double n3 = n * n * n, n4 = n3 * n;
        double var = 4.0 / n3 * sumhs2 - 4.0 / n4 * sumh * sumh + 1e-8;
        out[0] = (float)mmd2;
        out[1] = (float)var;
    }
}

extern "C" void kernel_launch(void* const* d_in, const int* in_sizes, int n_in,
                              void* d_out, int out_size, void* d_ws, size_t ws_size,
                              hipStream_t stream)
{
    const float* X   = (const float*)d_in[0];
    const float* Y   = (const float*)d_in[1];
    const float* W1  = (const float*)d_in[2];
    const float* b1  = (const float*)d_in[3];
    const float* W2  = (const float*)d_in[4];
    const float* b2  = (const float*)d_in[5];
    const float* W3  = (const float*)d_in[6];
    const float* b3  = (const float*)d_in[7];
    const float* W4  = (const float*)d_in[8];
    const float* b4  = (const float*)d_in[9];
    const float* ep  = (const float*)d_in[10];
    const float* sq  = (const float*)d_in[11];
    const float* sph = (const float*)d_in[12];
    float* out = (float*)d_out;

    char* ws = (char*)d_ws;
    float*  featsT = (float*)ws;                      // 52*8192*4 = 1703936
    float*  wOrg   = (float*)(ws + 1703936);          // 32768
    float*  D8     = (float*)(ws + 1736704);          // 32768
    double* S      = (double*)(ws + 1769472);         // 32 (Sxx, Syy, Sxy, trace)

    hipMemsetAsync(D8, 0, 32768 + 32, stream);

    mlp_kernel<<<256, 256, 0, stream>>>(X, Y, W1, b1, W2, b2, W3, b3, W4, b4,
                                        sq, featsT, wOrg);

    pair_kernel<<<2080, 256, 0, stream>>>(X, Y, featsT, wOrg, ep, sq, sph, D8, S);

    final_kernel<<<1, 256, 0, stream>>>(D8, S, out);
}

// Round 4
// 360.282 us; speedup vs baseline: 1.0681x; 1.0681x over previous
//
#include <hip/hip_runtime.h>
#include <math.h>

// DeepMMD round 4: despill. Phase order A (MFMA acc held) -> per-column-half
// {phase F (da 32 regs) + wave-private epilogue}. amdgpu_waves_per_eu(3,3)
// pins the allocator at 170 VGPR cap (round 3: it chose 84 and spilled 450MB
// of scratch traffic -> WRITE_SIZE 227MB, dur == hbm_bytes/1.55TB/s).
// LDS phase A: [sample][5 granules of 16B] stride-5 padding -> minimal b128 aliasing.

#define N_S 4096
#define LOG2E 1.4426950408889634

typedef _Float16 v8h __attribute__((ext_vector_type(8)));
typedef float v16f __attribute__((ext_vector_type(16)));
typedef float v2f __attribute__((ext_vector_type(2)));

union U16 { uint4 u; v8h h; };

// wave-internal LDS sync (lanes in lockstep; drain this wave's ds ops)
#define WAVE_LDS_SYNC() do {                                   \
    __builtin_amdgcn_wave_barrier();                           \
    asm volatile("s_waitcnt lgkmcnt(0)" ::: "memory");         \
    __builtin_amdgcn_wave_barrier();                           \
} while (0)

// ---------------- MLP: 256 blocks x 256 thr, 32 rows/block, k-split 8 ----------------
__global__ __launch_bounds__(256)
void mlp_kernel(const float* __restrict__ X, const float* __restrict__ Y,
                const float* __restrict__ W1, const float* __restrict__ b1,
                const float* __restrict__ W2, const float* __restrict__ b2,
                const float* __restrict__ W3, const float* __restrict__ b3,
                const float* __restrict__ W4, const float* __restrict__ b4,
                const float* __restrict__ sq,
                float* __restrict__ featsT, float* __restrict__ wOrg)
{
    __shared__ double sh[32 * 8 * 11];   // [row][chunk][z0..z9, nrm]
    int tid = threadIdx.x;
    int kk = tid & 7, r8 = tid >> 3;
    int row = blockIdx.x * 32 + r8;
    const float* xr = (row < N_S) ? (X + (size_t)row * 256) : (Y + (size_t)(row - N_S) * 256);

    double z[10];
#pragma unroll
    for (int j = 0; j < 10; ++j) z[j] = 0.0;
    double nrm = 0.0;
    for (int k4 = 0; k4 < 8; ++k4) {
        int kbase = kk * 32 + k4 * 4;
        float4 xv4 = *(const float4*)(xr + kbase);
        double xv[4] = {(double)xv4.x, (double)xv4.y, (double)xv4.z, (double)xv4.w};
#pragma unroll
        for (int u = 0; u < 4; ++u) {
            nrm += xv[u] * xv[u];
#pragma unroll
            for (int j = 0; j < 10; ++j) z[j] += xv[u] * (double)W1[(kbase + u) * 10 + j];
        }
    }
    double* slot = sh + (size_t)(r8 * 8 + kk) * 11;
#pragma unroll
    for (int j = 0; j < 10; ++j) slot[j] = z[j];
    slot[10] = nrm;
    __syncthreads();

    if (tid < 32) {
        int r = blockIdx.x * 32 + tid;
        double zz[10], nr = 0.0;
#pragma unroll
        for (int j = 0; j < 10; ++j) zz[j] = (double)b1[j];
        for (int s = 0; s < 8; ++s) {
            const double* p = sh + (size_t)(tid * 8 + s) * 11;
#pragma unroll
            for (int j = 0; j < 10; ++j) zz[j] += p[j];
            nr += p[10];
        }
#pragma unroll
        for (int j = 0; j < 10; ++j) zz[j] = fmax(zz[j], 0.0) + log1p(exp(-fabs(zz[j])));

        double z2[10];
#pragma unroll
        for (int j = 0; j < 10; ++j) z2[j] = (double)b2[j];
#pragma unroll
        for (int k = 0; k < 10; ++k)
#pragma unroll
            for (int j = 0; j < 10; ++j) z2[j] += zz[k] * (double)W2[k * 10 + j];
#pragma unroll
        for (int j = 0; j < 10; ++j) z2[j] = fmax(z2[j], 0.0) + log1p(exp(-fabs(z2[j])));

        double z3[10];
#pragma unroll
        for (int j = 0; j < 10; ++j) z3[j] = (double)b3[j];
#pragma unroll
        for (int k = 0; k < 10; ++k)
#pragma unroll
            for (int j = 0; j < 10; ++j) z3[j] += z2[k] * (double)W3[k * 10 + j];
#pragma unroll
        for (int j = 0; j < 10; ++j) z3[j] = fmax(z3[j], 0.0) + log1p(exp(-fabs(z3[j])));

        for (int j = 0; j < 50; ++j) {
            double f = (double)b4[j];
#pragma unroll
            for (int k = 0; k < 10; ++k) f += z3[k] * (double)W4[k * 50 + j];
            featsT[(size_t)j * 8192 + r] = (float)f;
        }
        featsT[(size_t)50 * 8192 + r] = 0.0f;
        featsT[(size_t)51 * 8192 + r] = 0.0f;

        double sqv = (double)sq[0];
        wOrg[r] = (float)exp2(-nr * (LOG2E / (sqv * sqv)));
    }
}

// ---------------- helpers ----------------
__device__ __forceinline__ v8h ldfrag(const uint4* buf, int s, int g) {
    U16 t; t.u = buf[s * 5 + g];   // stride-5 granule rows: gi%8 = (5s+g)%8 covers all quads
    return t.h;
}

__device__ __forceinline__ void cvt_split(float4 f0, float4 f1, uint4* hi, uint4* lo) {
    U16 H, L;
    float fv[8] = {f0.x, f0.y, f0.z, f0.w, f1.x, f1.y, f1.z, f1.w};
#pragma unroll
    for (int u = 0; u < 8; ++u) {
        _Float16 h = (_Float16)fv[u];
        H.h[u] = h;
        L.h[u] = (_Float16)(fv[u] - (float)h);
    }
    *hi = H.u; *lo = L.u;
}

// ---------------- joint pairwise pass ----------------
__global__ __launch_bounds__(256)
__attribute__((amdgpu_waves_per_eu(3, 3)))
void pair_kernel(const float* __restrict__ X, const float* __restrict__ Y,
                 const float* __restrict__ featsT, const float* __restrict__ wOrg,
                 const float* __restrict__ ep, const float* __restrict__ sq,
                 const float* __restrict__ sph,
                 float* __restrict__ D8, double* __restrict__ S)
{
    // LDS: phase A: 4 bufs x 128 rows x 5 granules x 16B = 40960
    //      per-half F: FA 26x132 f32 (13728) + FBh 26x68 (7072) = 20800
    //      epilogue: EB 4 waves x 16x68 f32 = 17408 @ 20800 (end 38208)
    __shared__ __align__(16) char smem[40960];

    int tid = threadIdx.x;
    int lane = tid & 63, w = tid >> 6;
    int h = lane >> 5, l31 = lane & 31, l15 = lane & 15, rg = lane >> 4;

    // upper-triangle tile decode
    int L = blockIdx.x, it = 0, span = 64;
    while (L >= span) { L -= span; --span; ++it; }
    int jt = it + L;

    bool sameHalf = (jt < 32) || (it >= 32);
    bool isDiag = (it == jt);
    bool isTrace = (jt == it + 32);
    int region = (jt < 32) ? 0 : ((it >= 32) ? 1 : 2);
    float sgn = sameHalf ? 1.0f : -1.0f;
    int i0 = it * 128, j0 = jt * 128;
    const float* aorg = (it < 32) ? X + (size_t)i0 * 256 : Y + (size_t)(i0 - N_S) * 256;
    const float* borg = (jt < 32) ? X + (size_t)j0 * 256 : Y + (size_t)(j0 - N_S) * 256;

    double epd = (double)ep[0];
    double eps = 1.0 / (1.0 + exp(-epd));
    double sqv = (double)sq[0], spv = (double)sph[0];
    float cf = (float)(LOG2E / (spv * spv));
    float twoco = (float)(2.0 * LOG2E / (sqv * sqv));
    float epsv = (float)eps, ome = (float)(1.0 - eps);

    // ---- phase A: fp16-split MFMA org dot; wave w: rows [32w,+32) x cols all ----
    uint4* Ahi = (uint4*)smem;
    uint4* Alo = Ahi + 640;
    uint4* Bhi = Ahi + 1280;
    uint4* Blo = Ahi + 1920;

    v16f acc[4];
#pragma unroll
    for (int c = 0; c < 4; ++c) acc[c] = (v16f)(0.0f);

    for (int kb = 0; kb < 256; kb += 32) {
        __syncthreads();
        for (int idx2 = tid; idx2 < 512; idx2 += 256) {
            int r = idx2 >> 2, g = idx2 & 3;
            int sw = r * 5 + g;
            const float* pa = aorg + (size_t)r * 256 + kb + g * 8;
            const float* pb = borg + (size_t)r * 256 + kb + g * 8;
            float4 fa0 = *(const float4*)pa, fa1 = *(const float4*)(pa + 4);
            float4 fb0 = *(const float4*)pb, fb1 = *(const float4*)(pb + 4);
            uint4 hi, lo;
            cvt_split(fa0, fa1, &hi, &lo); Ahi[sw] = hi; Alo[sw] = lo;
            cvt_split(fb0, fb1, &hi, &lo); Bhi[sw] = hi; Blo[sw] = lo;
        }
        __syncthreads();
#pragma unroll
        for (int ks = 0; ks < 2; ++ks) {
            int g = ks * 2 + h;
            int rs = 32 * w + l31;
            v8h ah = ldfrag(Ahi, rs, g);
            v8h al = ldfrag(Alo, rs, g);
#pragma unroll
            for (int c = 0; c < 4; ++c) {
                v8h bh = ldfrag(Bhi, 32 * c + l31, g);
                v8h bl = ldfrag(Blo, 32 * c + l31, g);
                acc[c] = __builtin_amdgcn_mfma_f32_32x32x16_f16(al, bh, acc[c], 0, 0, 0);
                acc[c] = __builtin_amdgcn_mfma_f32_32x32x16_f16(ah, bl, acc[c], 0, 0, 0);
                acc[c] = __builtin_amdgcn_mfma_f32_32x32x16_f16(ah, bh, acc[c], 0, 0, 0);
            }
        }
    }
    __syncthreads();   // phase-A LDS reads done before phase-F staging overwrites

    // ---- per column-half: phase F (exact fp32 feature dist) + epilogue ----
    float* FA  = (float*)smem;                       // 26 x 132
    float* FBh = (float*)(smem + 13728);             // 26 x 68
    float* EB  = (float*)(smem + 20800 + w * 4352);  // 16 x 68, wave-private
    double bsum = 0.0, trd = 0.0;
    int frow = 32 * w + rg * 8;

#pragma unroll
    for (int half = 0; half < 2; ++half) {
        v2f da[8][2];
#pragma unroll
        for (int i = 0; i < 8; ++i) { da[i][0] = (v2f)(0.0f); da[i][1] = (v2f)(0.0f); }

        for (int c0f = 0; c0f < 52; c0f += 26) {
            __syncthreads();   // prior epilogue/frag reads done
            for (int idx = tid; idx < 1248; idx += 256) {
                if (idx < 832) {
                    int k = idx >> 5, cg = (idx & 31) * 4;
                    *(float4*)&FA[k * 132 + cg] =
                        *(const float4*)&featsT[(size_t)(c0f + k) * 8192 + i0 + cg];
                } else {
                    int jx = idx - 832;
                    int k = jx >> 4, cg = (jx & 15) * 4;
                    *(float4*)&FBh[k * 68 + cg] =
                        *(const float4*)&featsT[(size_t)(c0f + k) * 8192 + j0 + 64 * half + cg];
                }
            }
            __syncthreads();
            for (int k = 0; k < 26; ++k) {
                float4 a0 = *(const float4*)&FA[k * 132 + frow];
                float4 a1 = *(const float4*)&FA[k * 132 + frow + 4];
                float4 b = *(const float4*)&FBh[k * 68 + l15 * 4];
                v2f b0; b0[0] = b.x; b0[1] = b.y;
                v2f b1; b1[0] = b.z; b1[1] = b.w;
                float av[8] = {a0.x, a0.y, a0.z, a0.w, a1.x, a1.y, a1.z, a1.w};
#pragma unroll
                for (int i = 0; i < 8; ++i) {
                    v2f ai; ai[0] = av[i]; ai[1] = av[i];
                    v2f t0 = ai - b0, t1 = ai - b1;
                    da[i][0] = t0 * t0 + da[i][0];
                    da[i][1] = t1 * t1 + da[i][1];
                }
            }
        }
#pragma unroll
        for (int i = 0; i < 8; ++i) {
            da[i][0][0] = exp2f(-da[i][0][0] * cf);
            da[i][0][1] = exp2f(-da[i][0][1] * cf);
            da[i][1][0] = exp2f(-da[i][1][0] * cf);
            da[i][1][1] = exp2f(-da[i][1][1] * cf);
        }

        // epilogue for this half (wave-private EB; acc[2h], acc[2h+1])
        float colacc0 = 0.0f, colacc1 = 0.0f;
        float wb0 = wOrg[j0 + 64 * half + l31];
        float wb1 = wOrg[j0 + 64 * half + 32 + l31];

#pragma unroll
        for (int r = 0; r < 2; ++r) {
            WAVE_LDS_SYNC();
            if ((rg >> 1) == r) {
                int rbase = (rg & 1) * 8;
#pragma unroll
                for (int i = 0; i < 8; ++i) {
                    float4 v;
                    v.x = da[i][0][0]; v.y = da[i][0][1];
                    v.z = da[i][1][0]; v.w = da[i][1][1];
                    *(float4*)&EB[(rbase + i) * 68 + l15 * 4] = v;
                }
            }
            WAVE_LDS_SYNC();
#pragma unroll
            for (int q = 0; q < 8; ++q) {
                int reg = 8 * r + q;
                int row_local = (q & 3) + 8 * (q >> 2) + 4 * h;
                int tile_row = 32 * w + 16 * r + row_local;
                float waq = wOrg[i0 + tile_row];
                float rsum = 0.0f;
                {
                    int col = 64 * half + l31;
                    float e2 = EB[row_local * 68 + l31];
                    float kv = waq * wb0 * exp2f(acc[2 * half][reg] * twoco) * (ome * e2 + epsv);
                    if (isDiag && tile_row == col) kv = 0.0f;
                    if (isTrace && col == tile_row) trd += (double)kv;
                    bsum += (double)kv; rsum += kv; colacc0 += kv;
                }
                {
                    int col = 64 * half + 32 + l31;
                    float e2 = EB[row_local * 68 + 32 + l31];
                    float kv = waq * wb1 * exp2f(acc[2 * half + 1][reg] * twoco) * (ome * e2 + epsv);
                    if (isDiag && tile_row == col) kv = 0.0f;
                    if (isTrace && col == tile_row) trd += (double)kv;
                    bsum += (double)kv; rsum += kv; colacc1 += kv;
                }
#pragma unroll
                for (int m = 1; m < 32; m <<= 1) rsum += __shfl_xor(rsum, m, 64);
                if (l31 == q) atomicAdd(&D8[i0 + tile_row], sgn * rsum);
            }
            WAVE_LDS_SYNC();
        }

        if (!isDiag) {
            float v0 = colacc0 + __shfl_xor(colacc0, 32, 64);
            float v1 = colacc1 + __shfl_xor(colacc1, 32, 64);
            if (h == 0) {
                atomicAdd(&D8[j0 + 64 * half + l31], sgn * v0);
                atomicAdd(&D8[j0 + 64 * half + 32 + l31], sgn * v1);
            }
        }
    }

    // total sum (+trace)
#pragma unroll
    for (int m = 1; m < 64; m <<= 1) bsum += __shfl_xor(bsum, m, 64);
    if (lane == 0) {
        double wgt = (sameHalf && !isDiag) ? 2.0 : 1.0;
        atomicAdd(&S[region], wgt * bsum);
    }
    if (isTrace) {
#pragma unroll
        for (int m = 1; m < 64; m <<= 1) trd += __shfl_xor(trd, m, 64);
        if (lane == 0) atomicAdd(&S[3], trd);
    }
}

// ---------------- final scalar assembly ----------------
__global__ __launch_bounds__(256)
void final_kernel(const float* __restrict__ D8, const double* __restrict__ S,
                  float* __restrict__ out)
{
    __shared__ double buf[512];
    int tid = threadIdx.x;
    double sD = 0, sD2 = 0;
    for (int i = tid; i < 4096; i += 256) {
        double d = (double)D8[i] + (double)D8[i + 4096];
        sD += d; sD2 += d * d;
    }
    buf[tid] = sD; buf[256 + tid] = sD2;
    __syncthreads();
    for (int s = 128; s > 0; s >>= 1) {
        if (tid < s) { buf[tid] += buf[tid + s]; buf[256 + tid] += buf[256 + tid + s]; }
        __syncthreads();
    }
    if (tid == 0) {
        double n = (double)N_S, D = n * (n - 1.0);
        double xx = S[0] / D, yy = S[1] / D, xy = (S[2] - S[3]) / D;
        double mmd2 = xx - 2.0 * xy + yy;
        double sumd = buf[0], sumd2 = buf[256];
        double sumh = 2.0 * n + sumd;                    // hs_i = 2 + delta_i
        double sumhs2 = 4.0 * n + 4.0 * sumd + sumd2;
        double n3 = n * n * n, n4 = n3 * n;
        double var = 4.0 / n3 * sumhs2 - 4.0 / n4 * sumh * sumh + 1e-8;
        out[0] = (float)mmd2;
        out[1] = (float)var;
    }
}

extern "C" void kernel_launch(void* const* d_in, const int* in_sizes, int n_in,
                              void* d_out, int out_size, void* d_ws, size_t ws_size,
                              hipStream_t stream)
{
    const float* X   = (const float*)d_in[0];
    const float* Y   = (const float*)d_in[1];
    const float* W1  = (const float*)d_in[2];
    const float* b1  = (const float*)d_in[3];
    const float* W2  = (const float*)d_in[4];
    const float* b2  = (const float*)d_in[5];
    const float* W3  = (const float*)d_in[6];
    const float* b3  = (const float*)d_in[7];
    const float* W4  = (const float*)d_in[8];
    const float* b4  = (const float*)d_in[9];
    const float* ep  = (const float*)d_in[10];
    const float* sq  = (const float*)d_in[11];
    const float* sph = (const float*)d_in[12];
    float* out = (float*)d_out;

    char* ws = (char*)d_ws;
    float*  featsT = (float*)ws;                      // 52*8192*4 = 1703936
    float*  wOrg   = (float*)(ws + 1703936);          // 32768
    float*  D8     = (float*)(ws + 1736704);          // 32768
    double* S      = (double*)(ws + 1769472);         // 32 (Sxx, Syy, Sxy, trace)

    hipMemsetAsync(D8, 0, 32768 + 32, stream);

    mlp_kernel<<<256, 256, 0, stream>>>(X, Y, W1, b1, W2, b2, W3, b3, W4, b4,
                                        sq, featsT, wOrg);

    pair_kernel<<<2080, 256, 0, stream>>>(X, Y, featsT, wOrg, ep, sq, sph, D8, S);

    final_kernel<<<1, 256, 0, stream>>>(D8, S, out);
}